// Round 7
// baseline (71.991 us; speedup 1.0000x reference)
//
#include <hip/hip_runtime.h>
#include <cfloat>
#include <climits>

#define B_   8
#define N1_  1024
#define N2_  4096
#define C_   256
#define TPQ  16                 // threads per query
#define QPB  (256 / TPQ)        // 16 queries per block

// ---------------------------------------------------------------------------
// Kernel 1: 3-NN search — byte-exact round-2/6 version (measured best).
// THIS ROUND: launched 3x as a timing instrument (idempotent: writes the
// same wsi/wsw every time; deterministic).
// ---------------------------------------------------------------------------

__device__ __forceinline__ bool better_(float d, int i, float D, int I) {
    return (d < D) || (d == D && i < I);   // lexicographic (d, index)
}

__device__ __forceinline__ void ins_(float d, int i,
                                     float& d0, float& d1, float& d2,
                                     int& i0, int& i1, int& i2) {
    if (better_(d, i, d2, i2)) {
        d2 = d; i2 = i;
        if (better_(d2, i2, d1, i1)) {
            float td = d1; d1 = d2; d2 = td;
            int   ti = i1; i1 = i2; i2 = ti;
            if (better_(d1, i1, d0, i0)) {
                td = d0; d0 = d1; d1 = td;
                ti = i0; i0 = i1; i1 = ti;
            }
        }
    }
}

__global__ __launch_bounds__(256) void knn_kernel(
    const float* __restrict__ p1, const float* __restrict__ p2,
    int4* __restrict__ wsi, float4* __restrict__ wsw) {
    __shared__ float4 pts[N1_];   // (2x, 2y, 2z, |p1|^2): 16 KB

    const int tid   = threadIdx.x;
    const int b     = blockIdx.x >> 8;     // N2/QPB = 256 tiles per batch
    const int mtile = blockIdx.x & 255;

    for (int j = tid; j < N1_; j += 256) {
        float x = p1[((size_t)b * N1_ + j) * 3 + 0];
        float y = p1[((size_t)b * N1_ + j) * 3 + 1];
        float z = p1[((size_t)b * N1_ + j) * 3 + 2];
        float s1 = __fadd_rn(__fadd_rn(__fmul_rn(x, x), __fmul_rn(y, y)),
                             __fmul_rn(z, z));
        pts[j] = make_float4(x + x, y + y, z + z, s1);  // 2x exact
    }
    __syncthreads();

    const int q = tid >> 4;       // query within tile
    const int t = tid & 15;       // sub-thread within query
    const int m = mtile * QPB + q;

    const size_t pbase = ((size_t)b * N2_ + m) * 3;
    const float x2 = p2[pbase + 0];
    const float y2 = p2[pbase + 1];
    const float z2 = p2[pbase + 2];
    const float s2 = __fadd_rn(__fadd_rn(__fmul_rn(x2, x2), __fmul_rn(y2, y2)),
                               __fmul_rn(z2, z2));

    float d0 = FLT_MAX, d1 = FLT_MAX, d2 = FLT_MAX;
    int   i0 = INT_MAX, i1 = INT_MAX, i2 = INT_MAX;

#pragma unroll 4
    for (int n = t; n < N1_; n += TPQ) {
        float4 p = pts[n];
        // dot2 == 2*dot bit-exactly (x2 scaling commutes with RN rounding)
        float dot2 = __fadd_rn(__fadd_rn(__fmul_rn(x2, p.x), __fmul_rn(y2, p.y)),
                               __fmul_rn(z2, p.z));
        float dd = __fadd_rn(__fsub_rn(s2, dot2), p.w);

        // branchless sorted insert (strict less; ascending n => index tiebreak)
        bool c0 = dd < d0;
        bool c1 = dd < d1;
        bool c2 = dd < d2;
        float n0 = fminf(dd, d0);
        float n1 = __builtin_amdgcn_fmed3f(dd, d0, d1);  // d0<=d1 sorted
        float n2 = __builtin_amdgcn_fmed3f(dd, d1, d2);
        int j0 = c0 ? n : i0;
        int j1 = c1 ? (c0 ? i0 : n) : i1;
        int j2 = c2 ? (c1 ? i1 : n) : i2;
        d0 = n0; d1 = n1; d2 = n2;
        i0 = j0; i1 = j1; i2 = j2;
    }

    // Butterfly-merge the 16 partial lists (exact (d,i) lexicographic).
    for (int mask = 1; mask < TPQ; mask <<= 1) {
        float pd0 = __shfl_xor(d0, mask, TPQ);
        float pd1 = __shfl_xor(d1, mask, TPQ);
        float pd2 = __shfl_xor(d2, mask, TPQ);
        int   pi0 = __shfl_xor(i0, mask, TPQ);
        int   pi1 = __shfl_xor(i1, mask, TPQ);
        int   pi2 = __shfl_xor(i2, mask, TPQ);
        ins_(pd0, pi0, d0, d1, d2, i0, i1, i2);
        ins_(pd1, pi1, d0, d1, d2, i0, i1, i2);
        ins_(pd2, pi2, d0, d1, d2, i0, i1, i2);
    }

    if (t == 0) {
        float r0 = 1.0f / __fadd_rn(d0, 1e-8f);
        float r1 = 1.0f / __fadd_rn(d1, 1e-8f);
        float r2 = 1.0f / __fadd_rn(d2, 1e-8f);
        float s  = __fadd_rn(__fadd_rn(r0, r1), r2);
        const size_t o = (size_t)b * N2_ + m;
        wsi[o] = make_int4(i0, i1, i2, 0);
        wsw[o] = make_float4(r0 / s, r1 / s, r2 / s, 0.0f);
    }
}

// ---------------------------------------------------------------------------
// Kernel 2 (v4): gather + blend — byte-exact round-6 version.
// ---------------------------------------------------------------------------

__global__ __launch_bounds__(256) void blend_kernel(
    const float* __restrict__ x1, const int4* __restrict__ wsi,
    const float4* __restrict__ wsw, float* __restrict__ out) {
    __shared__ float4 L4[N1_];   // 16 KB, XOR-swizzled channel-interleaved

    int bid = blockIdx.x;
    const int mhalf = bid & 1;
    const int ct    = (bid >> 1) & 63;   // 64 channel tiles of 4
    const int b     = bid >> 7;
    const int tid   = threadIdx.x;

    // Prefetch idx/weights for all 8 m-iterations.
    const size_t wbase = (size_t)b * N2_ + (size_t)mhalf * 2048;
    int4   id[8];
    float4 w[8];
#pragma unroll
    for (int mb = 0; mb < 8; ++mb) {
        id[mb] = wsi[wbase + mb * 256 + tid];
        w[mb]  = wsw[wbase + mb * 256 + tid];
    }

    // Stage 4 channels, register-transposed into interleaved LDS.
    const float* src = x1 + ((size_t)b * C_ + (size_t)ct * 4) * N1_;
    float4 v[4];
#pragma unroll
    for (int c = 0; c < 4; ++c)
        v[c] = reinterpret_cast<const float4*>(src + (size_t)c * N1_)[tid];
#pragma unroll
    for (int e = 0; e < 4; ++e) {
        const int n = 4 * tid + e;
        L4[n ^ ((n >> 3) & 7)] = make_float4((&v[0].x)[e], (&v[1].x)[e],
                                             (&v[2].x)[e], (&v[3].x)[e]);
    }
    __syncthreads();

    const size_t obase = ((size_t)b * C_ + (size_t)ct * 4) * N2_;
#pragma unroll
    for (int mb = 0; mb < 8; ++mb) {
        const int m = mhalf * 2048 + mb * 256 + tid;
        const int na = id[mb].x, nb = id[mb].y, nc = id[mb].z;
        const float4 A  = L4[na ^ ((na >> 3) & 7)];
        const float4 Bv = L4[nb ^ ((nb >> 3) & 7)];
        const float4 Cv = L4[nc ^ ((nc >> 3) & 7)];
        const float wx = w[mb].x, wy = w[mb].y, wz = w[mb].z;
#pragma unroll
        for (int r = 0; r < 4; ++r) {
            float acc = __fadd_rn(__fadd_rn(__fmul_rn((&A.x)[r],  wx),
                                            __fmul_rn((&Bv.x)[r], wy)),
                                  __fmul_rn((&Cv.x)[r], wz));
            __builtin_nontemporal_store(acc, &out[obase + (size_t)r * N2_ + m]);
        }
    }
}

extern "C" void kernel_launch(void* const* d_in, const int* in_sizes, int n_in,
                              void* d_out, int out_size, void* d_ws, size_t ws_size,
                              hipStream_t stream) {
    const float* p1 = (const float*)d_in[0];   // [B, N1, 3]
    const float* x1 = (const float*)d_in[1];   // [B, C, N1]
    const float* p2 = (const float*)d_in[2];   // [B, N2, 3]
    float* out = (float*)d_out;                // [B, C, N2]

    int4*   wsi = (int4*)d_ws;
    float4* wsw = (float4*)((char*)d_ws + (size_t)B_ * N2_ * sizeof(int4));

    // TIMING INSTRUMENT: knn launched 3x (idempotent, identical output).
    // dur_new - 33.07 = 2*(K + o) pins knn's per-launch cost.
    knn_kernel<<<B_ * (N2_ / QPB), 256, 0, stream>>>(p1, p2, wsi, wsw);
    knn_kernel<<<B_ * (N2_ / QPB), 256, 0, stream>>>(p1, p2, wsi, wsw);
    knn_kernel<<<B_ * (N2_ / QPB), 256, 0, stream>>>(p1, p2, wsi, wsw);
    blend_kernel<<<B_ * (C_ / 4) * 2, 256, 0, stream>>>(x1, wsi, wsw, out);
}

// Round 9
// 34.942 us; speedup vs baseline: 2.0603x; 2.0603x over previous
//
#include <hip/hip_runtime.h>
#include <cfloat>
#include <climits>

#define B_   8
#define N1_  1024
#define N2_  4096
#define C_   256
#define QPT  4      // queries per thread
#define QPB  32     // queries per block (8 slots x 4)

typedef float vf2 __attribute__((ext_vector_type(2)));

__device__ __forceinline__ unsigned umin_(unsigned a, unsigned b) { return a < b ? a : b; }
__device__ __forceinline__ unsigned umax_(unsigned a, unsigned b) { return a > b ? a : b; }

// Sorted-quad insert of packed key k, total u32 order. Invariant k0<=k1<=k2<=k3.
#define KINS4(k, k0, k1, k2, k3) do {                 \
    unsigned _n1 = umax_(k0, umin_((k), k1));         \
    unsigned _n2 = umax_(k1, umin_((k), k2));         \
    unsigned _n3 = umax_(k2, umin_((k), k3));         \
    k0 = umin_((k), k0);  k1 = _n1;  k2 = _n2;  k3 = _n3; \
} while (0)

// ---------------------------------------------------------------------------
// Kernel 1 (v6): 3-NN, truncated-key top-4 scan + EXACT rescue.
// - 4 queries/thread in registers; vf2 packed distance math (contract off;
//   pre-doubled coords make dot2 == 2*dot bit-exactly under RN)
// - scan key = (bits(max(dd,0)) & ~1023) | n  (u32 order == (trunc dist, idx))
// - top-4 survives any single trunc-tie at the 3|4 boundary (monotone trunc:
//   true top-3 ⊆ trunc top-4 unless >=2 simultaneous ties)
// - finalize: EXACT recompute of the 4 dists (reference bit order), exact
//   (d,idx) sort4, pick 3, reference-order weights. Output = weighted SUM
//   over the set => set-correct selection gives bit-correct output.
// ---------------------------------------------------------------------------
__global__ __launch_bounds__(256) void knn_kernel(
    const float* __restrict__ p1, const float* __restrict__ p2,
    int4* __restrict__ wsi, float4* __restrict__ wsw) {
#pragma clang fp contract(off)
    __shared__ float4 pts[N1_];   // (2x, 2y, 2z, |p1|^2): 16 KB

    const int tid   = threadIdx.x;
    const int b     = blockIdx.x >> 7;     // 128 query-tiles per batch
    const int mtile = blockIdx.x & 127;
    const int slice = tid & 31;            // candidate slice
    const int slot  = tid >> 5;            // 0..7 query slot
    const int mbase = mtile * QPB + slot * QPT;

    // This thread's 4 queries: 12 floats = 3 aligned float4 (48B granularity).
    const float4* P4 = reinterpret_cast<const float4*>(
        p2 + ((size_t)b * N2_ + mbase) * 3);
    const float4 f0 = P4[0], f1 = P4[1], f2 = P4[2];

    // Stage coarse points {2x,2y,2z,|p1|^2} (pre-double exact under RN).
    for (int j = tid; j < N1_; j += 256) {
        float x = p1[((size_t)b * N1_ + j) * 3 + 0];
        float y = p1[((size_t)b * N1_ + j) * 3 + 1];
        float z = p1[((size_t)b * N1_ + j) * 3 + 2];
        float s1 = __fadd_rn(__fadd_rn(__fmul_rn(x, x), __fmul_rn(y, y)),
                             __fmul_rn(z, z));
        pts[j] = make_float4(x + x, y + y, z + z, s1);
    }

    const float x0 = f0.x, y0 = f0.y, z0 = f0.z;
    const float x1q = f0.w, y1q = f1.x, z1q = f1.y;
    const float x2q = f1.z, y2q = f1.w, z2q = f2.x;
    const float x3q = f2.y, y3q = f2.z, z3q = f2.w;
    const vf2 xA = {x0, x1q}, xB = {x2q, x3q};
    const vf2 yA = {y0, y1q}, yB = {y2q, y3q};
    const vf2 zA = {z0, z1q}, zB = {z2q, z3q};
    const vf2 sA = (xA * xA + yA * yA) + zA * zA;   // (xx+yy)+zz, ref order
    const vf2 sB = (xB * xB + yB * yB) + zB * zB;

    __syncthreads();

    unsigned k00 = UINT_MAX, k01 = UINT_MAX, k02 = UINT_MAX, k03 = UINT_MAX;
    unsigned k10 = UINT_MAX, k11 = UINT_MAX, k12 = UINT_MAX, k13 = UINT_MAX;
    unsigned k20 = UINT_MAX, k21 = UINT_MAX, k22 = UINT_MAX, k23 = UINT_MAX;
    unsigned k30 = UINT_MAX, k31 = UINT_MAX, k32 = UINT_MAX, k33 = UINT_MAX;

#pragma unroll 8
    for (int j = 0; j < N1_ / 32; ++j) {
        const int n = j * 32 + slice;
        const float4 c = pts[n];
        const vf2 cx = {c.x, c.x}, cy = {c.y, c.y};
        const vf2 cz = {c.z, c.z}, cw = {c.w, c.w};
        const vf2 dA = (sA - ((xA * cx + yA * cy) + zA * cz)) + cw;
        const vf2 dB = (sB - ((xB * cx + yB * cy) + zB * cz)) + cw;
        const unsigned un = (unsigned)n;
        const unsigned q0 = (__float_as_uint(fmaxf(dA.x, 0.f)) & 0xFFFFFC00u) | un;
        const unsigned q1 = (__float_as_uint(fmaxf(dA.y, 0.f)) & 0xFFFFFC00u) | un;
        const unsigned q2 = (__float_as_uint(fmaxf(dB.x, 0.f)) & 0xFFFFFC00u) | un;
        const unsigned q3 = (__float_as_uint(fmaxf(dB.y, 0.f)) & 0xFFFFFC00u) | un;
        KINS4(q0, k00, k01, k02, k03);
        KINS4(q1, k10, k11, k12, k13);
        KINS4(q2, k20, k21, k22, k23);
        KINS4(q3, k30, k31, k32, k33);
    }

    // Butterfly-merge the 32 slices (u32 key order).
#pragma unroll
    for (int mask = 1; mask < 32; mask <<= 1) {
        unsigned p0, p1_, p2_, p3_;
        p0  = (unsigned)__shfl_xor((int)k00, mask, 32);
        p1_ = (unsigned)__shfl_xor((int)k01, mask, 32);
        p2_ = (unsigned)__shfl_xor((int)k02, mask, 32);
        p3_ = (unsigned)__shfl_xor((int)k03, mask, 32);
        KINS4(p0, k00, k01, k02, k03); KINS4(p1_, k00, k01, k02, k03);
        KINS4(p2_, k00, k01, k02, k03); KINS4(p3_, k00, k01, k02, k03);
        p0  = (unsigned)__shfl_xor((int)k10, mask, 32);
        p1_ = (unsigned)__shfl_xor((int)k11, mask, 32);
        p2_ = (unsigned)__shfl_xor((int)k12, mask, 32);
        p3_ = (unsigned)__shfl_xor((int)k13, mask, 32);
        KINS4(p0, k10, k11, k12, k13); KINS4(p1_, k10, k11, k12, k13);
        KINS4(p2_, k10, k11, k12, k13); KINS4(p3_, k10, k11, k12, k13);
        p0  = (unsigned)__shfl_xor((int)k20, mask, 32);
        p1_ = (unsigned)__shfl_xor((int)k21, mask, 32);
        p2_ = (unsigned)__shfl_xor((int)k22, mask, 32);
        p3_ = (unsigned)__shfl_xor((int)k23, mask, 32);
        KINS4(p0, k20, k21, k22, k23); KINS4(p1_, k20, k21, k22, k23);
        KINS4(p2_, k20, k21, k22, k23); KINS4(p3_, k20, k21, k22, k23);
        p0  = (unsigned)__shfl_xor((int)k30, mask, 32);
        p1_ = (unsigned)__shfl_xor((int)k31, mask, 32);
        p2_ = (unsigned)__shfl_xor((int)k32, mask, 32);
        p3_ = (unsigned)__shfl_xor((int)k33, mask, 32);
        KINS4(p0, k30, k31, k32, k33); KINS4(p1_, k30, k31, k32, k33);
        KINS4(p2_, k30, k31, k32, k33); KINS4(p3_, k30, k31, k32, k33);
    }

    // Slices 0..3 finalize query (mbase + slice): exact rescue of 4 -> 3.
    if (slice < QPT) {
        const unsigned a0 = slice == 0 ? k00 : slice == 1 ? k10 : slice == 2 ? k20 : k30;
        const unsigned a1 = slice == 0 ? k01 : slice == 1 ? k11 : slice == 2 ? k21 : k31;
        const unsigned a2 = slice == 0 ? k02 : slice == 1 ? k12 : slice == 2 ? k22 : k32;
        const unsigned a3 = slice == 0 ? k03 : slice == 1 ? k13 : slice == 2 ? k23 : k33;
        const float qx = slice == 0 ? x0 : slice == 1 ? x1q : slice == 2 ? x2q : x3q;
        const float qy = slice == 0 ? y0 : slice == 1 ? y1q : slice == 2 ? y2q : y3q;
        const float qz = slice == 0 ? z0 : slice == 1 ? z1q : slice == 2 ? z2q : z3q;
        const float qs = slice == 0 ? sA.x : slice == 1 ? sA.y : slice == 2 ? sB.x : sB.y;

        int   ix[4];
        float dx[4];
#pragma unroll
        for (int k = 0; k < 4; ++k) {
            const unsigned a = k == 0 ? a0 : k == 1 ? a1 : k == 2 ? a2 : a3;
            const int n = (int)(a & 1023u);
            const float4 c = pts[n];
            // EXACT reference arithmetic: dd = (s2 - dot2) + s1
            dx[k] = __fadd_rn(__fsub_rn(qs,
                __fadd_rn(__fadd_rn(__fmul_rn(qx, c.x), __fmul_rn(qy, c.y)),
                          __fmul_rn(qz, c.z))), c.w);
            ix[k] = n;
        }
        // Exact lexicographic (d, idx) sort-4 network: (0,1)(2,3)(0,2)(1,3)(1,2)
#define CSWAP(a, b) do {                                            \
        bool sw = (dx[b] < dx[a]) || (dx[b] == dx[a] && ix[b] < ix[a]); \
        float td = sw ? dx[b] : dx[a]; dx[b] = sw ? dx[a] : dx[b]; dx[a] = td; \
        int   ti = sw ? ix[b] : ix[a]; ix[b] = sw ? ix[a] : ix[b]; ix[a] = ti; \
    } while (0)
        CSWAP(0, 1); CSWAP(2, 3); CSWAP(0, 2); CSWAP(1, 3); CSWAP(1, 2);
#undef CSWAP

        const float r0 = 1.0f / __fadd_rn(dx[0], 1e-8f);
        const float r1 = 1.0f / __fadd_rn(dx[1], 1e-8f);
        const float r2 = 1.0f / __fadd_rn(dx[2], 1e-8f);
        const float s  = __fadd_rn(__fadd_rn(r0, r1), r2);
        const size_t o = (size_t)b * N2_ + mbase + slice;
        wsi[o] = make_int4(ix[0], ix[1], ix[2], 0);
        wsw[o] = make_float4(r0 / s, r1 / s, r2 / s, 0.0f);
    }
}

// ---------------------------------------------------------------------------
// Kernel 2 (v4): gather + blend — byte-exact round-6 version (control).
// ---------------------------------------------------------------------------

__global__ __launch_bounds__(256) void blend_kernel(
    const float* __restrict__ x1, const int4* __restrict__ wsi,
    const float4* __restrict__ wsw, float* __restrict__ out) {
    __shared__ float4 L4[N1_];   // 16 KB, XOR-swizzled channel-interleaved

    int bid = blockIdx.x;
    const int mhalf = bid & 1;
    const int ct    = (bid >> 1) & 63;   // 64 channel tiles of 4
    const int b     = bid >> 7;
    const int tid   = threadIdx.x;

    // Prefetch idx/weights for all 8 m-iterations.
    const size_t wbase = (size_t)b * N2_ + (size_t)mhalf * 2048;
    int4   id[8];
    float4 w[8];
#pragma unroll
    for (int mb = 0; mb < 8; ++mb) {
        id[mb] = wsi[wbase + mb * 256 + tid];
        w[mb]  = wsw[wbase + mb * 256 + tid];
    }

    // Stage 4 channels, register-transposed into interleaved LDS.
    const float* src = x1 + ((size_t)b * C_ + (size_t)ct * 4) * N1_;
    float4 v[4];
#pragma unroll
    for (int c = 0; c < 4; ++c)
        v[c] = reinterpret_cast<const float4*>(src + (size_t)c * N1_)[tid];
#pragma unroll
    for (int e = 0; e < 4; ++e) {
        const int n = 4 * tid + e;
        L4[n ^ ((n >> 3) & 7)] = make_float4((&v[0].x)[e], (&v[1].x)[e],
                                             (&v[2].x)[e], (&v[3].x)[e]);
    }
    __syncthreads();

    const size_t obase = ((size_t)b * C_ + (size_t)ct * 4) * N2_;
#pragma unroll
    for (int mb = 0; mb < 8; ++mb) {
        const int m = mhalf * 2048 + mb * 256 + tid;
        const int na = id[mb].x, nb = id[mb].y, nc = id[mb].z;
        const float4 A  = L4[na ^ ((na >> 3) & 7)];
        const float4 Bv = L4[nb ^ ((nb >> 3) & 7)];
        const float4 Cv = L4[nc ^ ((nc >> 3) & 7)];
        const float wx = w[mb].x, wy = w[mb].y, wz = w[mb].z;
#pragma unroll
        for (int r = 0; r < 4; ++r) {
            float acc = __fadd_rn(__fadd_rn(__fmul_rn((&A.x)[r],  wx),
                                            __fmul_rn((&Bv.x)[r], wy)),
                                  __fmul_rn((&Cv.x)[r], wz));
            __builtin_nontemporal_store(acc, &out[obase + (size_t)r * N2_ + m]);
        }
    }
}

extern "C" void kernel_launch(void* const* d_in, const int* in_sizes, int n_in,
                              void* d_out, int out_size, void* d_ws, size_t ws_size,
                              hipStream_t stream) {
    const float* p1 = (const float*)d_in[0];   // [B, N1, 3]
    const float* x1 = (const float*)d_in[1];   // [B, C, N1]
    const float* p2 = (const float*)d_in[2];   // [B, N2, 3]
    float* out = (float*)d_out;                // [B, C, N2]

    int4*   wsi = (int4*)d_ws;
    float4* wsw = (float4*)((char*)d_ws + (size_t)B_ * N2_ * sizeof(int4));

    knn_kernel<<<B_ * (N2_ / QPB), 256, 0, stream>>>(p1, p2, wsi, wsw);
    blend_kernel<<<B_ * (C_ / 4) * 2, 256, 0, stream>>>(x1, wsi, wsw, out);
}